// Round 1
// baseline (732.080 us; speedup 1.0000x reference)
//
#include <hip/hip_runtime.h>
#include <hip/hip_bf16.h>
#include <stdint.h>

#define N_ATOMS   100000
#define N_BONDS   200000
#define N_MOLS    4000
#define MAX_NB    6
#define ATOM_FDIM 133
#define BOND_FDIM 14
#define HIDDEN    300
#define NPAD      320
#define KPAD_I    160
#define KPAD_H    320
#define KPAD_O    448

typedef __attribute__((ext_vector_type(8))) short          bf16x8;
typedef __attribute__((ext_vector_type(8))) unsigned short u16x8;
typedef __attribute__((ext_vector_type(4))) float          f32x4;

__device__ __forceinline__ float bf2f(unsigned short u) {
  union { unsigned int i; float f; } v; v.i = ((unsigned int)u) << 16; return v.f;
}
__device__ __forceinline__ unsigned short f2bf(float f) {
  union { float f; unsigned int i; } v; v.f = f;
  unsigned int u = v.i;
  return (unsigned short)((u + 0x7fffu + ((u >> 16) & 1u)) >> 16);
}

// ---- weight pad/convert: out[NPAD][KP] bf16 from in[N][K] f32, zero pad ----
__global__ void convw_kernel(const float* __restrict__ w, unsigned short* __restrict__ o,
                             int N, int K, int KP) {
  int total = NPAD * KP;
  for (int idx = blockIdx.x * 256 + threadIdx.x; idx < total; idx += gridDim.x * 256) {
    int n = idx / KP, k = idx - n * KP;
    float v = (n < N && k < K) ? w[n * K + k] : 0.f;
    o[idx] = f2bf(v);
  }
}

// ---- neighbor aggregate: nei[a][:] = sum_j msg[a2b[a][j]][:] ----
__global__ void agg_kernel(const unsigned short* __restrict__ msg,
                           const int* __restrict__ a2b,
                           unsigned short* __restrict__ nei) {
  int idx = blockIdx.x * 256 + threadIdx.x;
  const int total = N_ATOMS * (NPAD / 8);
  if (idx >= total) return;
  int a  = idx / (NPAD / 8);
  int kc = (idx - a * (NPAD / 8)) * 8;
  float s[8];
#pragma unroll
  for (int e = 0; e < 8; e++) s[e] = 0.f;
#pragma unroll
  for (int j = 0; j < MAX_NB; j++) {
    int b = a2b[a * MAX_NB + j];
    u16x8 v = *(const u16x8*)&msg[(size_t)b * NPAD + kc];
#pragma unroll
    for (int e = 0; e < 8; e++) s[e] += bf2f(v[e]);
  }
  u16x8 o;
#pragma unroll
  for (int e = 0; e < 8; e++) o[e] = f2bf(s[e]);
  *(u16x8*)&nei[(size_t)a * NPAD + kc] = o;
}

// ---- fused-staging MFMA GEMM: out[M][NPAD] = relu(A @ W^T (+bias)) ----
// SRC=0: A[b][k] = k<133 ? f_atoms[b2a[b]][k] : k<147 ? f_bonds[b][k-133] : 0   (KP=160)
// SRC=1: A[b][k] = nei[b2a[b]][k] - msg[b2revb[b]][k]                           (KP=320)
// SRC=2: A[a][k] = k<133 ? f_atoms[a][k] : k<433 ? amsg[a][k-133] : 0           (KP=448)
template<int SRC>
__global__ __launch_bounds__(256) void gemm64_kernel(
    const float* __restrict__ f_atoms, const float* __restrict__ f_bonds,
    const int* __restrict__ b2a, const int* __restrict__ b2revb,
    const unsigned short* __restrict__ nei,  // SRC1: nei; SRC2: amsg
    const unsigned short* msgin,             // SRC1 only (may alias out)
    const unsigned short* __restrict__ W,    // bf16 [NPAD][KP]
    const float* __restrict__ bias,          // SRC2 only
    unsigned short* out, int M, int KP) {
  __shared__ __align__(16) unsigned short As[64 * 32];

  const int b0   = blockIdx.x * 64;
  const int tid  = threadIdx.x;
  const int lane = tid & 63;
  const int wave = tid >> 6;
  const int sr   = tid >> 2;          // staging row 0..63
  const int skc  = (tid & 3) * 8;     // staging k offset

  int row = b0 + sr;
  if (row >= M) row = M - 1;
  int gatherRow = 0, revRow = 0;
  if (SRC == 0 || SRC == 1) gatherRow = b2a[row];
  if (SRC == 1) revRow = b2revb[row];

  f32x4 acc[4][5];
#pragma unroll
  for (int m = 0; m < 4; m++)
#pragma unroll
    for (int n = 0; n < 5; n++) acc[m][n] = (f32x4){0.f, 0.f, 0.f, 0.f};

  const int nbase = wave * 80;
  const unsigned short* Wl = W + (size_t)(nbase + (lane & 15)) * KP + ((lane >> 4) * 8);
  const int a_off = (lane & 15) * 32 + (lane >> 4) * 8;

  const int nsteps = KP / 32;
  for (int ks = 0; ks < nsteps; ks++) {
    const int k0 = ks * 32;
    unsigned short vals[8];
    if (SRC == 0) {
#pragma unroll
      for (int j = 0; j < 8; j++) {
        int k = k0 + skc + j;
        float v = 0.f;
        if (k < ATOM_FDIM)                  v = f_atoms[(size_t)gatherRow * ATOM_FDIM + k];
        else if (k < ATOM_FDIM + BOND_FDIM) v = f_bonds[(size_t)row * BOND_FDIM + (k - ATOM_FDIM)];
        vals[j] = f2bf(v);
      }
    } else if (SRC == 1) {
      u16x8 n8 = *(const u16x8*)&nei[(size_t)gatherRow * NPAD + k0 + skc];
      u16x8 m8 = *(const u16x8*)&msgin[(size_t)revRow * NPAD + k0 + skc];
#pragma unroll
      for (int j = 0; j < 8; j++) vals[j] = f2bf(bf2f(n8[j]) - bf2f(m8[j]));
    } else {
#pragma unroll
      for (int j = 0; j < 8; j++) {
        int k = k0 + skc + j;
        float v = 0.f;
        if (k < ATOM_FDIM)               v = f_atoms[(size_t)row * ATOM_FDIM + k];
        else if (k < ATOM_FDIM + HIDDEN) v = bf2f(nei[(size_t)row * NPAD + (k - ATOM_FDIM)]);
        vals[j] = f2bf(v);
      }
    }
    __syncthreads();  // protect previous iteration's LDS reads
    *(u16x8*)&As[sr * 32 + skc] = *(const u16x8*)vals;
    __syncthreads();

    bf16x8 afrag[4];
#pragma unroll
    for (int m = 0; m < 4; m++) afrag[m] = *(const bf16x8*)&As[a_off + m * 16 * 32];
#pragma unroll
    for (int nf = 0; nf < 5; nf++) {
      bf16x8 bfrag = *(const bf16x8*)(Wl + (size_t)nf * 16 * KP + k0);
#pragma unroll
      for (int m = 0; m < 4; m++)
        acc[m][nf] = __builtin_amdgcn_mfma_f32_16x16x32_bf16(afrag[m], bfrag, acc[m][nf], 0, 0, 0);
    }
  }

  // epilogue: D row = m*16 + (lane>>4)*4 + r, col = nbase + nf*16 + (lane&15)
#pragma unroll
  for (int m = 0; m < 4; m++) {
#pragma unroll
    for (int r = 0; r < 4; r++) {
      int orow = b0 + m * 16 + (lane >> 4) * 4 + r;
      if (orow >= M) continue;
#pragma unroll
      for (int nf = 0; nf < 5; nf++) {
        int ocol = nbase + nf * 16 + (lane & 15);
        float v = acc[m][nf][r];
        if (SRC == 2) v += (ocol < HIDDEN) ? bias[ocol] : 0.f;
        v = v > 0.f ? v : 0.f;
        out[(size_t)orow * NPAD + ocol] = f2bf(v);
      }
    }
  }
}

// ---- per-molecule mean readout ----
__global__ void readout_kernel(const unsigned short* __restrict__ hidden,
                               const int* __restrict__ a_scope,
                               float* __restrict__ out) {
  int idx = blockIdx.x * 256 + threadIdx.x;
  const int total = N_MOLS * HIDDEN;
  if (idx >= total) return;
  int m = idx / HIDDEN, c = idx - m * HIDDEN;
  int start = a_scope[m * 2], size = a_scope[m * 2 + 1];
  float s = 0.f;
  for (int i = 0; i < size; i++) s += bf2f(hidden[(size_t)(start + i) * NPAD + c]);
  out[idx] = (size > 0) ? s / (float)size : 0.f;
}

extern "C" void kernel_launch(void* const* d_in, const int* in_sizes, int n_in,
                              void* d_out, int out_size, void* d_ws, size_t ws_size,
                              hipStream_t stream) {
  const float* f_atoms = (const float*)d_in[0];
  const float* f_bonds = (const float*)d_in[1];
  const int*   a2b     = (const int*)d_in[2];
  const int*   b2a     = (const int*)d_in[3];
  const int*   b2revb  = (const int*)d_in[4];
  const int*   a_scope = (const int*)d_in[5];
  const float* W_i     = (const float*)d_in[6];
  const float* W_h     = (const float*)d_in[7];
  const float* W_o     = (const float*)d_in[8];
  const float* b_o     = (const float*)d_in[9];
  float* out = (float*)d_out;

  char* ws = (char*)d_ws;
  size_t off = 0;
  auto alloc = [&](size_t bytes) { size_t o = off; off += (bytes + 255) & ~(size_t)255; return o; };
  unsigned short* msg    = (unsigned short*)(ws + alloc((size_t)N_BONDS * NPAD * 2)); // 128 MB
  unsigned short* nei    = (unsigned short*)(ws + alloc((size_t)N_ATOMS * NPAD * 2)); //  64 MB
  unsigned short* hidden = (unsigned short*)(ws + alloc((size_t)N_ATOMS * NPAD * 2)); //  64 MB
  unsigned short* Wi_bf  = (unsigned short*)(ws + alloc((size_t)NPAD * KPAD_I * 2));
  unsigned short* Wh_bf  = (unsigned short*)(ws + alloc((size_t)NPAD * KPAD_H * 2));
  unsigned short* Wo_bf  = (unsigned short*)(ws + alloc((size_t)NPAD * KPAD_O * 2));

  // 1) weights -> bf16 padded
  convw_kernel<<<(NPAD * KPAD_I + 255) / 256, 256, 0, stream>>>(W_i, Wi_bf, HIDDEN, ATOM_FDIM + BOND_FDIM, KPAD_I);
  convw_kernel<<<(NPAD * KPAD_H + 255) / 256, 256, 0, stream>>>(W_h, Wh_bf, HIDDEN, HIDDEN, KPAD_H);
  convw_kernel<<<(NPAD * KPAD_O + 255) / 256, 256, 0, stream>>>(W_o, Wo_bf, HIDDEN, ATOM_FDIM + HIDDEN, KPAD_O);

  const int gb = N_BONDS / 64;             // 3125
  const int ga = (N_ATOMS + 63) / 64;      // 1563

  // 2) message0 = relu(concat(f_atoms[b2a], f_bonds) @ W_i^T)
  gemm64_kernel<0><<<gb, 256, 0, stream>>>(f_atoms, f_bonds, b2a, b2revb, nullptr, nullptr,
                                           Wi_bf, nullptr, msg, N_BONDS, KPAD_I);
  // 3) two message-passing rounds (GEMM in-place: reads of msg stay in-block)
  for (int d = 0; d < 2; d++) {
    agg_kernel<<<(N_ATOMS * (NPAD / 8)) / 256, 256, 0, stream>>>(msg, a2b, nei);
    gemm64_kernel<1><<<gb, 256, 0, stream>>>(f_atoms, f_bonds, b2a, b2revb, nei, msg,
                                             Wh_bf, nullptr, msg, N_BONDS, KPAD_H);
  }
  // 4) final aggregate -> amsg (in nei buffer)
  agg_kernel<<<(N_ATOMS * (NPAD / 8)) / 256, 256, 0, stream>>>(msg, a2b, nei);
  // 5) atom_hiddens = relu(concat(f_atoms, amsg) @ W_o^T + b_o)
  gemm64_kernel<2><<<ga, 256, 0, stream>>>(f_atoms, f_bonds, b2a, b2revb, nei, nullptr,
                                           Wo_bf, b_o, hidden, N_ATOMS, KPAD_O);
  // 6) per-molecule mean
  readout_kernel<<<(N_MOLS * HIDDEN + 255) / 256, 256, 0, stream>>>(hidden, a_scope, out);
}

// Round 2
// 730.394 us; speedup vs baseline: 1.0023x; 1.0023x over previous
//
#include <hip/hip_runtime.h>
#include <hip/hip_bf16.h>
#include <stdint.h>

#define N_ATOMS   100000
#define N_BONDS   200000
#define N_MOLS    4000
#define MAX_NB    6
#define ATOM_FDIM 133
#define BOND_FDIM 14
#define HIDDEN    300
#define NPAD      320
#define KPAD_I    160
#define KPAD_H    320
#define KPAD_O    448

typedef __attribute__((ext_vector_type(8))) short          bf16x8;
typedef __attribute__((ext_vector_type(8))) unsigned short u16x8;
typedef __attribute__((ext_vector_type(4))) float          f32x4;

__device__ __forceinline__ float bf2f(unsigned short u) {
  union { unsigned int i; float f; } v; v.i = ((unsigned int)u) << 16; return v.f;
}
__device__ __forceinline__ unsigned short f2bf(float f) {
  union { float f; unsigned int i; } v; v.f = f;
  unsigned int u = v.i;
  return (unsigned short)((u + 0x7fffu + ((u >> 16) & 1u)) >> 16);
}

// ---- weight pad/convert: out[NPAD][KP] bf16 from in[N][K] f32, zero pad ----
__global__ void convw_kernel(const float* __restrict__ w, unsigned short* __restrict__ o,
                             int N, int K, int KP) {
  int total = NPAD * KP;
  for (int idx = blockIdx.x * 256 + threadIdx.x; idx < total; idx += gridDim.x * 256) {
    int n = idx / KP, k = idx - n * KP;
    float v = (n < N && k < K) ? w[n * K + k] : 0.f;
    o[idx] = f2bf(v);
  }
}

// ---- neighbor aggregate: nei[a][:] = sum_j msg[a2b[a][j]][:] ----
__global__ void agg_kernel(const unsigned short* __restrict__ msg,
                           const int* __restrict__ a2b,
                           unsigned short* __restrict__ nei) {
  int idx = blockIdx.x * 256 + threadIdx.x;
  const int total = N_ATOMS * (NPAD / 8);
  if (idx >= total) return;
  int a  = idx / (NPAD / 8);
  int kc = (idx - a * (NPAD / 8)) * 8;
  float s[8];
#pragma unroll
  for (int e = 0; e < 8; e++) s[e] = 0.f;
#pragma unroll
  for (int j = 0; j < MAX_NB; j++) {
    int b = a2b[a * MAX_NB + j];
    u16x8 v = *(const u16x8*)&msg[(size_t)b * NPAD + kc];
#pragma unroll
    for (int e = 0; e < 8; e++) s[e] += bf2f(v[e]);
  }
  u16x8 o;
#pragma unroll
  for (int e = 0; e < 8; e++) o[e] = f2bf(s[e]);
  *(u16x8*)&nei[(size_t)a * NPAD + kc] = o;
}

// ---- per-(SRC) staging load of one 8-element chunk ----
template<int SRC>
__device__ __forceinline__ u16x8 stage_load(
    int ks, int q, int row, int gatherRow, int revRow,
    const float* __restrict__ f_atoms, const float* __restrict__ f_bonds,
    const unsigned short* __restrict__ nei, const unsigned short* msgin) {
  const int kc = ks * 32 + q * 8;
  u16x8 r;
  if (SRC == 1) {
    u16x8 n8 = *(const u16x8*)&nei[(size_t)gatherRow * NPAD + kc];
    u16x8 m8 = *(const u16x8*)&msgin[(size_t)revRow * NPAD + kc];
#pragma unroll
    for (int j = 0; j < 8; j++) r[j] = f2bf(bf2f(n8[j]) - bf2f(m8[j]));
  } else if (SRC == 0) {
#pragma unroll
    for (int j = 0; j < 8; j++) {
      int k = kc + j; float v = 0.f;
      if (k < ATOM_FDIM)                  v = f_atoms[(size_t)gatherRow * ATOM_FDIM + k];
      else if (k < ATOM_FDIM + BOND_FDIM) v = f_bonds[(size_t)row * BOND_FDIM + (k - ATOM_FDIM)];
      r[j] = f2bf(v);
    }
  } else {
#pragma unroll
    for (int j = 0; j < 8; j++) {
      int k = kc + j; float v = 0.f;
      if (k < ATOM_FDIM)               v = f_atoms[(size_t)row * ATOM_FDIM + k];
      else if (k < ATOM_FDIM + HIDDEN) v = bf2f(nei[(size_t)row * NPAD + (k - ATOM_FDIM)]);
      r[j] = f2bf(v);
    }
  }
  return r;
}

// ---- fused-staging MFMA GEMM, whole-A-tile upfront staging, 1 barrier ----
// LDS layout is fragment-major: As[ks][m][lane] -> 16B per lane, conflict-free
// both on the staging write and the MFMA read.
// SRC=0: A[b][k] = concat(f_atoms[b2a[b]], f_bonds[b], 0)                (KP=160)
// SRC=1: A[b][k] = nei[b2a[b]][k] - msg[b2revb[b]][k]                    (KP=320)
// SRC=2: A[a][k] = concat(f_atoms[a], amsg[a], 0)                        (KP=448)
template<int SRC>
__global__ __launch_bounds__(256, 2) void gemm64_kernel(
    const float* __restrict__ f_atoms, const float* __restrict__ f_bonds,
    const int* __restrict__ b2a, const int* __restrict__ b2revb,
    const unsigned short* __restrict__ nei,  // SRC1: nei; SRC2: amsg
    const unsigned short* msgin,             // SRC1 only (may alias out)
    const unsigned short* __restrict__ W,    // bf16 [NPAD][KP]
    const float* __restrict__ bias,          // SRC2 only
    unsigned short* out, int M) {
  constexpr int KP  = (SRC == 0) ? KPAD_I : (SRC == 1) ? KPAD_H : KPAD_O;
  constexpr int NST = KP / 32;
  __shared__ __align__(16) unsigned short As[NST * 2048];

  const int b0   = blockIdx.x * 64;
  const int tid  = threadIdx.x;
  const int lane = tid & 63;
  const int wave = tid >> 6;
  const int sr   = tid >> 2;          // staging row 0..63
  const int q    = tid & 3;           // staging col-quarter

  int row = b0 + sr;
  if (row >= M) row = M - 1;
  int gatherRow = 0, revRow = 0;
  if (SRC == 0 || SRC == 1) gatherRow = b2a[row];
  if (SRC == 1) revRow = b2revb[row];

  // frag-major destination: elem = ks*2048 + (sr>>4)*512 + (q*16 + (sr&15))*8
  const int dbase = (sr >> 4) * 512 + (q * 16 + (sr & 15)) * 8;

  // ---- stage whole A tile, groups of 5 k-steps (10 loads in flight) ----
  constexpr int G = 5;
#pragma unroll
  for (int ks0 = 0; ks0 < NST; ks0 += G) {
    u16x8 vals[G];
#pragma unroll
    for (int j = 0; j < G; j++) {
      const int ks = ks0 + j;
      if (ks < NST)
        vals[j] = stage_load<SRC>(ks, q, row, gatherRow, revRow, f_atoms, f_bonds, nei, msgin);
    }
#pragma unroll
    for (int j = 0; j < G; j++) {
      const int ks = ks0 + j;
      if (ks < NST) *(u16x8*)&As[ks * 2048 + dbase] = vals[j];
    }
  }
  __syncthreads();

  // ---- MFMA sweep, no barriers ----
  f32x4 acc[4][5];
#pragma unroll
  for (int m = 0; m < 4; m++)
#pragma unroll
    for (int n = 0; n < 5; n++) acc[m][n] = (f32x4){0.f, 0.f, 0.f, 0.f};

  const int nbase = wave * 80;
  const unsigned short* Wl = W + (size_t)(nbase + (lane & 15)) * KP + ((lane >> 4) * 8);

#pragma unroll
  for (int ks = 0; ks < NST; ks++) {
    bf16x8 afrag[4];
#pragma unroll
    for (int m = 0; m < 4; m++)
      afrag[m] = *(const bf16x8*)&As[ks * 2048 + m * 512 + lane * 8];
#pragma unroll
    for (int nf = 0; nf < 5; nf++) {
      bf16x8 bfrag = *(const bf16x8*)(Wl + (size_t)nf * 16 * KP + ks * 32);
#pragma unroll
      for (int m = 0; m < 4; m++)
        acc[m][nf] = __builtin_amdgcn_mfma_f32_16x16x32_bf16(afrag[m], bfrag, acc[m][nf], 0, 0, 0);
    }
  }

  // epilogue: D row = m*16 + (lane>>4)*4 + r, col = nbase + nf*16 + (lane&15)
#pragma unroll
  for (int m = 0; m < 4; m++) {
#pragma unroll
    for (int r = 0; r < 4; r++) {
      int orow = b0 + m * 16 + (lane >> 4) * 4 + r;
      if (orow >= M) continue;
#pragma unroll
      for (int nf = 0; nf < 5; nf++) {
        int ocol = nbase + nf * 16 + (lane & 15);
        float v = acc[m][nf][r];
        if (SRC == 2) v += (ocol < HIDDEN) ? bias[ocol] : 0.f;
        v = v > 0.f ? v : 0.f;
        out[(size_t)orow * NPAD + ocol] = f2bf(v);
      }
    }
  }
}

// ---- per-molecule mean readout ----
__global__ void readout_kernel(const unsigned short* __restrict__ hidden,
                               const int* __restrict__ a_scope,
                               float* __restrict__ out) {
  int idx = blockIdx.x * 256 + threadIdx.x;
  const int total = N_MOLS * HIDDEN;
  if (idx >= total) return;
  int m = idx / HIDDEN, c = idx - m * HIDDEN;
  int start = a_scope[m * 2], size = a_scope[m * 2 + 1];
  float s = 0.f;
  for (int i = 0; i < size; i++) s += bf2f(hidden[(size_t)(start + i) * NPAD + c]);
  out[idx] = (size > 0) ? s / (float)size : 0.f;
}

extern "C" void kernel_launch(void* const* d_in, const int* in_sizes, int n_in,
                              void* d_out, int out_size, void* d_ws, size_t ws_size,
                              hipStream_t stream) {
  const float* f_atoms = (const float*)d_in[0];
  const float* f_bonds = (const float*)d_in[1];
  const int*   a2b     = (const int*)d_in[2];
  const int*   b2a     = (const int*)d_in[3];
  const int*   b2revb  = (const int*)d_in[4];
  const int*   a_scope = (const int*)d_in[5];
  const float* W_i     = (const float*)d_in[6];
  const float* W_h     = (const float*)d_in[7];
  const float* W_o     = (const float*)d_in[8];
  const float* b_o     = (const float*)d_in[9];
  float* out = (float*)d_out;

  char* ws = (char*)d_ws;
  size_t off = 0;
  auto alloc = [&](size_t bytes) { size_t o = off; off += (bytes + 255) & ~(size_t)255; return o; };
  unsigned short* msg    = (unsigned short*)(ws + alloc((size_t)N_BONDS * NPAD * 2)); // 128 MB
  unsigned short* nei    = (unsigned short*)(ws + alloc((size_t)N_ATOMS * NPAD * 2)); //  64 MB
  unsigned short* hidden = (unsigned short*)(ws + alloc((size_t)N_ATOMS * NPAD * 2)); //  64 MB
  unsigned short* Wi_bf  = (unsigned short*)(ws + alloc((size_t)NPAD * KPAD_I * 2));
  unsigned short* Wh_bf  = (unsigned short*)(ws + alloc((size_t)NPAD * KPAD_H * 2));
  unsigned short* Wo_bf  = (unsigned short*)(ws + alloc((size_t)NPAD * KPAD_O * 2));

  // 1) weights -> bf16 padded
  convw_kernel<<<(NPAD * KPAD_I + 255) / 256, 256, 0, stream>>>(W_i, Wi_bf, HIDDEN, ATOM_FDIM + BOND_FDIM, KPAD_I);
  convw_kernel<<<(NPAD * KPAD_H + 255) / 256, 256, 0, stream>>>(W_h, Wh_bf, HIDDEN, HIDDEN, KPAD_H);
  convw_kernel<<<(NPAD * KPAD_O + 255) / 256, 256, 0, stream>>>(W_o, Wo_bf, HIDDEN, ATOM_FDIM + HIDDEN, KPAD_O);

  const int gb = N_BONDS / 64;             // 3125
  const int ga = (N_ATOMS + 63) / 64;      // 1563

  // 2) message0 = relu(concat(f_atoms[b2a], f_bonds) @ W_i^T)
  gemm64_kernel<0><<<gb, 256, 0, stream>>>(f_atoms, f_bonds, b2a, b2revb, nullptr, nullptr,
                                           Wi_bf, nullptr, msg, N_BONDS);
  // 3) two message-passing rounds (GEMM in-place: reads of msg stay in-block)
  for (int d = 0; d < 2; d++) {
    agg_kernel<<<(N_ATOMS * (NPAD / 8)) / 256, 256, 0, stream>>>(msg, a2b, nei);
    gemm64_kernel<1><<<gb, 256, 0, stream>>>(f_atoms, f_bonds, b2a, b2revb, nei, msg,
                                             Wh_bf, nullptr, msg, N_BONDS);
  }
  // 4) final aggregate -> amsg (in nei buffer)
  agg_kernel<<<(N_ATOMS * (NPAD / 8)) / 256, 256, 0, stream>>>(msg, a2b, nei);
  // 5) atom_hiddens = relu(concat(f_atoms, amsg) @ W_o^T + b_o)
  gemm64_kernel<2><<<ga, 256, 0, stream>>>(f_atoms, f_bonds, b2a, b2revb, nei, nullptr,
                                           Wo_bf, b_o, hidden, N_ATOMS);
  // 6) per-molecule mean
  readout_kernel<<<(N_MOLS * HIDDEN + 255) / 256, 256, 0, stream>>>(hidden, a_scope, out);
}